// Round 6
// baseline (1460.373 us; speedup 1.0000x reference)
//
#include <hip/hip_runtime.h>
#include <hip/hip_bf16.h>

// WindowAttention (Swin) on MI355X — round 6
//   Change vs R5: k_gemm rewritten as a ZERO-LDS, ZERO-BARRIER register GEMM.
//   Evidence: R3/R4/R5 all ~420us for BOTH qkv (12 Kstep x 14112 blk) and
//   proj (36 Kstep x 4704 blk) -> time scales with barrier-synced K-steps,
//   i.e. per-step exposed load latency. B is L2-resident (weights < 1MB bf16),
//   A is L2-reused across same-XCD n-blocks, so frags load global->reg
//   directly (k_attn already validates this pattern). Latency hidden by
//   ILP (unroll 2) + TLP (no LDS -> more resident waves).
//   k_attn / k_cvt / k_cvt_w unchanged.

typedef __attribute__((ext_vector_type(8))) short bf16x8;
typedef __attribute__((ext_vector_type(4))) float f32x4;

#define SEQ_N  49
#define CH     384
#define QKV_N  1152
#define HDIM   32
#define UNIT_ROWS 3136   // 64 windows * 49 rows

__device__ __forceinline__ unsigned short f2b(float f) {
    union { float f; unsigned int u; } v; v.f = f;
    return (unsigned short)((v.u + 0x7FFFu + ((v.u >> 16) & 1u)) >> 16);
}

__device__ __forceinline__ bf16x8 ld8(const unsigned short* p) {
    return *(const bf16x8*)p;    // 16B-aligned at every call site
}

// bijective XCD-chunking swizzle (m204)
__device__ __forceinline__ int xcd_swizzle(int orig, int T) {
    int q = T >> 3, r = T & 7;
    int xcd = orig & 7, idx = orig >> 3;
    return (xcd < r ? xcd * (q + 1) : r * (q + 1) + (xcd - r) * q) + idx;
}

// ---------------- weight convert+transpose: Bt[n][k] = bf16(W[k][n]) --------
__global__ __launch_bounds__(256) void k_cvt_w(const float* __restrict__ wq,
        const float* __restrict__ wp, unsigned short* __restrict__ oq,
        unsigned short* __restrict__ op)
{
    int t = blockIdx.x * 256 + threadIdx.x;
    if (t < QKV_N * CH) {
        int n = t / CH, k = t - n * CH;
        oq[t] = f2b(wq[(size_t)k * QKV_N + n]);
    }
    if (t < CH * CH) {
        int n = t / CH, k = t - n * CH;
        op[t] = f2b(wp[(size_t)k * CH + n]);
    }
}

// ---------------- x fp32 -> bf16 (vectorized, grid-stride) -------------------
__global__ __launch_bounds__(256) void k_cvt(const float* __restrict__ in,
        unsigned short* __restrict__ outp, int n8)
{
    int stride = gridDim.x * 256;
    for (int i = blockIdx.x * 256 + threadIdx.x; i < n8; i += stride) {
        const float4* p = (const float4*)(in + (size_t)i * 8);
        float4 a = p[0], b = p[1];
        uint4 v;
        v.x = (unsigned)f2b(a.x) | ((unsigned)f2b(a.y) << 16);
        v.y = (unsigned)f2b(a.z) | ((unsigned)f2b(a.w) << 16);
        v.z = (unsigned)f2b(b.x) | ((unsigned)f2b(b.y) << 16);
        v.w = (unsigned)f2b(b.z) | ((unsigned)f2b(b.w) << 16);
        *(uint4*)(outp + (size_t)i * 8) = v;
    }
}

// ---------------- register GEMM: C[M][ldc] = A @ Bt^T + bias -----------------
// A bf16 row-major [M][lda], Bt bf16 n-major [N][K]. No LDS, no barriers:
// MFMA fragments load directly global->reg (L1/L2-served).
template<int OUTF32>
__global__ __launch_bounds__(256) void k_gemm(
        const unsigned short* __restrict__ A, int lda,
        const unsigned short* __restrict__ Bt, int K,
        const float* __restrict__ bias,
        unsigned short* __restrict__ Cb, float* __restrict__ Cf, int ldc,
        int M, int ntiles, int mtiles)
{
    const int wg = xcd_swizzle(blockIdx.x, mtiles * ntiles);
    const int m0 = (wg / ntiles) * 128;
    const int n0 = (wg % ntiles) * 128;
    const int tid = threadIdx.x;
    const int lane = tid & 63, wid = tid >> 6;
    const int wm = (wid >> 1) * 64, wn = (wid & 1) * 64;
    const int l15 = lane & 15, g = lane >> 4;

    // per-lane fragment base pointers
    const unsigned short* ap[4];
    const unsigned short* bp[4];
#pragma unroll
    for (int mt = 0; mt < 4; ++mt) {
        int r = m0 + wm + mt * 16 + l15;
        if (r > M - 1) r = M - 1;        // clamped rows never stored
        ap[mt] = A + (size_t)r * lda + g * 8;
    }
#pragma unroll
    for (int nt = 0; nt < 4; ++nt)
        bp[nt] = Bt + (size_t)(n0 + wn + nt * 16 + l15) * K + g * 8;

    f32x4 acc[4][4];
#pragma unroll
    for (int a = 0; a < 4; ++a)
#pragma unroll
        for (int b = 0; b < 4; ++b) acc[a][b] = (f32x4){0.f, 0.f, 0.f, 0.f};

#pragma unroll 2
    for (int kt = 0; kt < K; kt += 32) {
        bf16x8 af[4], bfr[4];
#pragma unroll
        for (int mt = 0; mt < 4; ++mt) af[mt] = ld8(ap[mt] + kt);
#pragma unroll
        for (int nt = 0; nt < 4; ++nt) bfr[nt] = ld8(bp[nt] + kt);
#pragma unroll
        for (int mt = 0; mt < 4; ++mt)
#pragma unroll
            for (int nt = 0; nt < 4; ++nt)
                acc[mt][nt] = __builtin_amdgcn_mfma_f32_16x16x32_bf16(
                        af[mt], bfr[nt], acc[mt][nt], 0, 0, 0);
    }

    // ---- epilogue: scalar stores (form proven time-neutral R3 vs R4)
#pragma unroll
    for (int mt = 0; mt < 4; ++mt)
#pragma unroll
        for (int nt = 0; nt < 4; ++nt) {
            int col = n0 + wn + nt * 16 + l15;
            float bb = bias[col];
#pragma unroll
            for (int r = 0; r < 4; ++r) {
                int row = m0 + wm + mt * 16 + g * 4 + r;
                if (row < M) {
                    if (OUTF32)
                        Cf[(size_t)row * ldc + col] = acc[mt][nt][r] + bb;
                    else
                        Cb[(size_t)row * ldc + col] = f2b(acc[mt][nt][r] + bb);
                }
            }
        }
}

// ---------------- attention: 1 wave per (window, head) -----------------------
__global__ __launch_bounds__(256) void k_attn(unsigned short* __restrict__ qkv,
        const float* __restrict__ mask, const float* __restrict__ btab, int win_base)
{
    extern __shared__ unsigned short sm[];
    const int tid = threadIdx.x;
    const int lane = tid & 63, wv = tid >> 6;
    const int l15 = lane & 15, g = lane >> 4;
    const int pair = blockIdx.x * 4 + wv;
    const int winloc = pair / 12;
    const int h = pair - winloc * 12;
    const int wimg = (win_base + winloc) & 63;
    const int co = h * HDIM;
    unsigned short* Vt = sm + wv * 6912;     // [32][72]  V^T
    unsigned short* Pw = Vt + 32 * 72;       // [64][72]  P
    unsigned short* src = qkv + (size_t)winloc * SEQ_N * QKV_N;

    for (int t = lane; t < 32 * 16; t += 64) {
        int c = t >> 4, kk = 48 + (t & 15);
        Vt[c * 72 + kk] = 0;
    }
    for (int t = lane; t < 49 * 4; t += 64) {
        int row = t >> 2, cb = (t & 3) * 8;
        const unsigned short* vp = src + (size_t)row * QKV_N + 768 + co + cb;
        ushort4 a = ((const ushort4*)vp)[0];
        ushort4 b = ((const ushort4*)vp)[1];
        Vt[(cb + 0) * 72 + row] = a.x; Vt[(cb + 1) * 72 + row] = a.y;
        Vt[(cb + 2) * 72 + row] = a.z; Vt[(cb + 3) * 72 + row] = a.w;
        Vt[(cb + 4) * 72 + row] = b.x; Vt[(cb + 5) * 72 + row] = b.y;
        Vt[(cb + 6) * 72 + row] = b.z; Vt[(cb + 7) * 72 + row] = b.w;
    }

    bf16x8 qf[4], kf[4];
#pragma unroll
    for (int mt = 0; mt < 4; ++mt) {
        int r = mt * 16 + l15; if (r > 48) r = 48;
        qf[mt] = ld8(src + (size_t)r * QKV_N + co + g * 8);
    }
#pragma unroll
    for (int nt = 0; nt < 4; ++nt) {
        int r = nt * 16 + l15; if (r > 48) r = 48;
        kf[nt] = ld8(src + (size_t)r * QKV_N + CH + co + g * 8);
    }

    f32x4 sa[4][4];
#pragma unroll
    for (int mt = 0; mt < 4; ++mt)
#pragma unroll
        for (int nt = 0; nt < 4; ++nt) sa[mt][nt] = (f32x4){0.f, 0.f, 0.f, 0.f};
#pragma unroll
    for (int mt = 0; mt < 4; ++mt)
#pragma unroll
        for (int nt = 0; nt < 4; ++nt)
            sa[mt][nt] = __builtin_amdgcn_mfma_f32_16x16x32_bf16(
                    qf[mt], kf[nt], sa[mt][nt], 0, 0, 0);

    int jj[4], jh[4], jw4[4];
#pragma unroll
    for (int nt = 0; nt < 4; ++nt) {
        int j = nt * 16 + l15;
        jj[nt] = j; jh[nt] = j / 7; jw4[nt] = j - (j / 7) * 7;
    }
    const float scale = 0.17677669529663687f;
#pragma unroll
    for (int mt = 0; mt < 4; ++mt) {
#pragma unroll
        for (int r = 0; r < 4; ++r) {
            int i = mt * 16 + g * 4 + r;
            int ic = i < 49 ? i : 48;
            int ih = ic / 7, iw = ic - (ic / 7) * 7;
            const float* mrow = mask + (size_t)wimg * 2401 + ic * 49;
            float sv[4];
#pragma unroll
            for (int nt = 0; nt < 4; ++nt) {
                float s = sa[mt][nt][r];
                if (jj[nt] < 49) {
                    int idx = (ih - jh[nt] + 6) * 13 + (iw - jw4[nt] + 6);
                    s = s * scale + btab[idx * 12 + h] + mrow[jj[nt]];
                } else s = -1e30f;
                sv[nt] = s;
            }
            float mx = fmaxf(fmaxf(sv[0], sv[1]), fmaxf(sv[2], sv[3]));
#pragma unroll
            for (int d = 1; d < 16; d <<= 1) mx = fmaxf(mx, __shfl_xor(mx, d));
            float sum = 0.f;
#pragma unroll
            for (int nt = 0; nt < 4; ++nt) { sv[nt] = __expf(sv[nt] - mx); sum += sv[nt]; }
#pragma unroll
            for (int d = 1; d < 16; d <<= 1) sum += __shfl_xor(sum, d);
            float inv = 1.0f / sum;
#pragma unroll
            for (int nt = 0; nt < 4; ++nt)
                Pw[i * 72 + nt * 16 + l15] = f2b(sv[nt] * inv);
        }
    }
    __syncthreads();

    f32x4 oa[4][2];
#pragma unroll
    for (int mt = 0; mt < 4; ++mt)
#pragma unroll
        for (int nt = 0; nt < 2; ++nt) oa[mt][nt] = (f32x4){0.f, 0.f, 0.f, 0.f};
#pragma unroll
    for (int ks = 0; ks < 2; ++ks) {
        bf16x8 pf[4];
#pragma unroll
        for (int mt = 0; mt < 4; ++mt)
            pf[mt] = ld8(Pw + (mt * 16 + l15) * 72 + ks * 32 + g * 8);
#pragma unroll
        for (int nt = 0; nt < 2; ++nt) {
            bf16x8 vf = ld8(Vt + (nt * 16 + l15) * 72 + ks * 32 + g * 8);
#pragma unroll
            for (int mt = 0; mt < 4; ++mt)
                oa[mt][nt] = __builtin_amdgcn_mfma_f32_16x16x32_bf16(
                        pf[mt], vf, oa[mt][nt], 0, 0, 0);
        }
    }

#pragma unroll
    for (int mt = 0; mt < 4; ++mt)
#pragma unroll
        for (int r = 0; r < 4; ++r) {
            int i = mt * 16 + g * 4 + r;
            if (i < 49) {
#pragma unroll
                for (int nt = 0; nt < 2; ++nt)
                    src[(size_t)i * QKV_N + co + nt * 16 + l15] = f2b(oa[mt][nt][r]);
            }
        }
}

extern "C" void kernel_launch(void* const* d_in, const int* in_sizes, int n_in,
                              void* d_out, int out_size, void* d_ws, size_t ws_size,
                              hipStream_t stream) {
    const float* x      = (const float*)d_in[0];
    const float* mask   = (const float*)d_in[1];
    const float* qkv_w  = (const float*)d_in[2];
    const float* qkv_b  = (const float*)d_in[3];
    const float* proj_w = (const float*)d_in[4];
    const float* proj_b = (const float*)d_in[5];
    const float* btab   = (const float*)d_in[6];
    float* out = (float*)d_out;

    unsigned short* wq_bt = (unsigned short*)d_ws;
    unsigned short* wp_bt = wq_bt + QKV_N * CH;
    unsigned short* base  = wp_bt + CH * CH;
    const size_t fixed = (size_t)(QKV_N * CH + CH * CH) * 2;
    const size_t unit  = (size_t)UNIT_ROWS * (CH + QKV_N) * 2;
    if (ws_size < fixed + unit) return;
    int upc = (int)((ws_size - fixed) / unit);
    if (upc > 64) upc = 64;
    unsigned short* xb  = base;
    unsigned short* qkv = base + (size_t)upc * UNIT_ROWS * CH;

    const int smem2 = 4 * 6912 * 2;   // 55,296 B -> 2 blocks/CU
    hipFuncSetAttribute(reinterpret_cast<const void*>(k_attn),
                        hipFuncAttributeMaxDynamicSharedMemorySize, smem2);

    dim3 blk(256);
    k_cvt_w<<<dim3((QKV_N * CH + 255) / 256), blk, 0, stream>>>(qkv_w, proj_w, wq_bt, wp_bt);

    for (int u0 = 0; u0 < 64; u0 += upc) {
        int units = (64 - u0) < upc ? (64 - u0) : upc;
        int m_base = u0 * UNIT_ROWS;
        int Mc = units * UNIT_ROWS;
        int mtiles = (Mc + 127) / 128;
        k_cvt<<<dim3(2048), blk, 0, stream>>>(x + (size_t)m_base * CH, xb, Mc * 48);
        k_gemm<0><<<dim3(mtiles * 9), blk, 0, stream>>>(
                xb, CH, wq_bt, CH, qkv_b, qkv, nullptr, QKV_N, Mc, 9, mtiles);
        k_attn<<<dim3(units * 192), blk, smem2, stream>>>(qkv, mask, btab, u0);
        k_gemm<1><<<dim3(mtiles * 3), blk, 0, stream>>>(
                qkv, QKV_N, wp_bt, CH, proj_b, nullptr, out + (size_t)m_base * CH,
                CH, Mc, 3, mtiles);
    }
}

// Round 7
// 1038.940 us; speedup vs baseline: 1.4056x; 1.4056x over previous
//
#include <hip/hip_runtime.h>
#include <hip/hip_bf16.h>

// WindowAttention (Swin) on MI355X — round 7
//   Change vs R5/R6: k_gemm back to LDS staging (R6 reg-GEMM regressed), now
//   with a REAL pipeline: 3 LDS buffers, depth-2 prefetch, raw s_barrier +
//   counted "s_waitcnt vmcnt(8)" (T4). R5's __syncthreads drained vmcnt(0)
//   including the just-issued prefetch -> zero overlap; counted waits only
//   wait for loads issued two steps (~800cyc) earlier.
//   k_attn / k_cvt / k_cvt_w unchanged.

typedef __attribute__((ext_vector_type(8))) short bf16x8;
typedef __attribute__((ext_vector_type(4))) float f32x4;

#define SEQ_N  49
#define CH     384
#define QKV_N  1152
#define HDIM   32
#define UNIT_ROWS 3136   // 64 windows * 49 rows

__device__ __forceinline__ unsigned short f2b(float f) {
    union { float f; unsigned int u; } v; v.f = f;
    return (unsigned short)((v.u + 0x7FFFu + ((v.u >> 16) & 1u)) >> 16);
}

__device__ __forceinline__ bf16x8 ld8(const unsigned short* p) {
    return *(const bf16x8*)p;    // 16B-aligned at every call site
}

// async global->LDS, 16B per lane; lds dst must be wave-uniform base
__device__ __forceinline__ void gload16(const unsigned short* g, unsigned short* l) {
    __builtin_amdgcn_global_load_lds(
        (const __attribute__((address_space(1))) unsigned int*)g,
        (__attribute__((address_space(3))) unsigned int*)l, 16, 0, 0);
}

// bijective XCD-chunking swizzle (m204)
__device__ __forceinline__ int xcd_swizzle(int orig, int T) {
    int q = T >> 3, r = T & 7;
    int xcd = orig & 7, idx = orig >> 3;
    return (xcd < r ? xcd * (q + 1) : r * (q + 1) + (xcd - r) * q) + idx;
}

// ---------------- weight convert+transpose: Bt[n][k] = bf16(W[k][n]) --------
__global__ __launch_bounds__(256) void k_cvt_w(const float* __restrict__ wq,
        const float* __restrict__ wp, unsigned short* __restrict__ oq,
        unsigned short* __restrict__ op)
{
    int t = blockIdx.x * 256 + threadIdx.x;
    if (t < QKV_N * CH) {
        int n = t / CH, k = t - n * CH;
        oq[t] = f2b(wq[(size_t)k * QKV_N + n]);
    }
    if (t < CH * CH) {
        int n = t / CH, k = t - n * CH;
        op[t] = f2b(wp[(size_t)k * CH + n]);
    }
}

// ---------------- x fp32 -> bf16 (vectorized, grid-stride) -------------------
__global__ __launch_bounds__(256) void k_cvt(const float* __restrict__ in,
        unsigned short* __restrict__ outp, int n8)
{
    int stride = gridDim.x * 256;
    for (int i = blockIdx.x * 256 + threadIdx.x; i < n8; i += stride) {
        const float4* p = (const float4*)(in + (size_t)i * 8);
        float4 a = p[0], b = p[1];
        uint4 v;
        v.x = (unsigned)f2b(a.x) | ((unsigned)f2b(a.y) << 16);
        v.y = (unsigned)f2b(a.z) | ((unsigned)f2b(a.w) << 16);
        v.z = (unsigned)f2b(b.x) | ((unsigned)f2b(b.y) << 16);
        v.w = (unsigned)f2b(b.z) | ((unsigned)f2b(b.w) << 16);
        *(uint4*)(outp + (size_t)i * 8) = v;
    }
}

// ---------------- pipelined GEMM: C[M][ldc] = A @ Bt^T + bias ----------------
// A bf16 row-major [M][lda], Bt bf16 n-major [N][K]. 128x128 tile, BK=32,
// 3-buffer LDS, depth-2 prefetch, counted vmcnt (never 0 in main loop).
template<int OUTF32>
__global__ __launch_bounds__(256) void k_gemm(
        const unsigned short* __restrict__ A, int lda,
        const unsigned short* __restrict__ Bt, int K,
        const float* __restrict__ bias,
        unsigned short* __restrict__ Cb, float* __restrict__ Cf, int ldc,
        int M, int ntiles, int mtiles)
{
    __shared__ unsigned short As[3 * 4096];
    __shared__ unsigned short Bs[3 * 4096];
    const int wg = xcd_swizzle(blockIdx.x, mtiles * ntiles);
    const int m0 = (wg / ntiles) * 128;
    const int n0 = (wg % ntiles) * 128;
    const int tid = threadIdx.x;
    const int lane = tid & 63, wid = tid >> 6;
    const int wm = (wid >> 1) * 64, wn = (wid & 1) * 64;
    const int l15 = lane & 15, g = lane >> 4;

    f32x4 acc[4][4];
#pragma unroll
    for (int a = 0; a < 4; ++a)
#pragma unroll
        for (int b = 0; b < 4; ++b) acc[a][b] = (f32x4){0.f, 0.f, 0.f, 0.f};

    const int r0 = wid * 16 + (lane >> 2);
    const int kofs = (lane & 3) * 8;
    int ra0 = m0 + r0;       if (ra0 > M - 1) ra0 = M - 1;
    int ra1 = m0 + 64 + r0;  if (ra1 > M - 1) ra1 = M - 1;
    const unsigned short* a0p = A + (size_t)ra0 * lda + kofs;
    const unsigned short* a1p = A + (size_t)ra1 * lda + kofs;
    const unsigned short* b0p = Bt + (size_t)(n0 + r0) * K + kofs;
    const unsigned short* b1p = Bt + (size_t)(n0 + 64 + r0) * K + kofs;
    const int lo = wid * 512;          // wave-uniform LDS offset

#define STAGE(kt, buf) do {                                   \
        gload16(a0p + (kt), &As[(buf) * 4096 + lo]);          \
        gload16(a1p + (kt), &As[(buf) * 4096 + 2048 + lo]);   \
        gload16(b0p + (kt), &Bs[(buf) * 4096 + lo]);          \
        gload16(b1p + (kt), &Bs[(buf) * 4096 + 2048 + lo]);   \
    } while (0)

#define COMPUTE(buf) do {                                                     \
        bf16x8 af[4], bfr[4];                                                 \
        _Pragma("unroll")                                                     \
        for (int mt = 0; mt < 4; ++mt)                                        \
            af[mt] = ld8(&As[(buf) * 4096 + (wm + mt * 16 + l15) * 32 + g * 8]); \
        _Pragma("unroll")                                                     \
        for (int nt = 0; nt < 4; ++nt)                                        \
            bfr[nt] = ld8(&Bs[(buf) * 4096 + (wn + nt * 16 + l15) * 32 + g * 8]); \
        _Pragma("unroll")                                                     \
        for (int mt = 0; mt < 4; ++mt)                                        \
            _Pragma("unroll")                                                 \
            for (int nt = 0; nt < 4; ++nt)                                    \
                acc[mt][nt] = __builtin_amdgcn_mfma_f32_16x16x32_bf16(        \
                        af[mt], bfr[nt], acc[mt][nt], 0, 0, 0);               \
    } while (0)

    const int nsteps = K >> 5;         // 12 (qkv) or 36 (proj)

    // prologue: stage tiles 0 and 1
    STAGE(0, 0);
    STAGE(32, 1);

    int cur = 0;
    for (int t = 0; t < nsteps - 2; ++t) {
        int pf = cur + 2; if (pf >= 3) pf -= 3;
        STAGE((t + 2) * 32, pf);                   // 4 more in flight (12 total)
        __builtin_amdgcn_sched_barrier(0);
        asm volatile("s_waitcnt vmcnt(8)" ::: "memory");   // tile t's 4 done
        __builtin_amdgcn_sched_barrier(0);
        __builtin_amdgcn_s_barrier();              // all waves' tile-t loads done
        __builtin_amdgcn_sched_barrier(0);
        COMPUTE(cur);
        __builtin_amdgcn_sched_barrier(0);
        __builtin_amdgcn_s_barrier();              // all waves done reading cur
        __builtin_amdgcn_sched_barrier(0);
        cur = (cur == 2) ? 0 : cur + 1;
    }
    // step nsteps-2: 8 outstanding, wait for its 4
    asm volatile("s_waitcnt vmcnt(4)" ::: "memory");
    __builtin_amdgcn_sched_barrier(0);
    __builtin_amdgcn_s_barrier();
    __builtin_amdgcn_sched_barrier(0);
    COMPUTE(cur);
    cur = (cur == 2) ? 0 : cur + 1;
    // step nsteps-1: drain
    asm volatile("s_waitcnt vmcnt(0)" ::: "memory");
    __builtin_amdgcn_sched_barrier(0);
    __builtin_amdgcn_s_barrier();
    __builtin_amdgcn_sched_barrier(0);
    COMPUTE(cur);
#undef STAGE
#undef COMPUTE

    // ---- epilogue: scalar stores (form proven time-neutral R3 vs R4)
#pragma unroll
    for (int mt = 0; mt < 4; ++mt)
#pragma unroll
        for (int nt = 0; nt < 4; ++nt) {
            int col = n0 + wn + nt * 16 + l15;
            float bb = bias[col];
#pragma unroll
            for (int r = 0; r < 4; ++r) {
                int row = m0 + wm + mt * 16 + g * 4 + r;
                if (row < M) {
                    if (OUTF32)
                        Cf[(size_t)row * ldc + col] = acc[mt][nt][r] + bb;
                    else
                        Cb[(size_t)row * ldc + col] = f2b(acc[mt][nt][r] + bb);
                }
            }
        }
}

// ---------------- attention: 1 wave per (window, head) -----------------------
__global__ __launch_bounds__(256) void k_attn(unsigned short* __restrict__ qkv,
        const float* __restrict__ mask, const float* __restrict__ btab, int win_base)
{
    extern __shared__ unsigned short sm[];
    const int tid = threadIdx.x;
    const int lane = tid & 63, wv = tid >> 6;
    const int l15 = lane & 15, g = lane >> 4;
    const int pair = blockIdx.x * 4 + wv;
    const int winloc = pair / 12;
    const int h = pair - winloc * 12;
    const int wimg = (win_base + winloc) & 63;
    const int co = h * HDIM;
    unsigned short* Vt = sm + wv * 6912;     // [32][72]  V^T
    unsigned short* Pw = Vt + 32 * 72;       // [64][72]  P
    unsigned short* src = qkv + (size_t)winloc * SEQ_N * QKV_N;

    for (int t = lane; t < 32 * 16; t += 64) {
        int c = t >> 4, kk = 48 + (t & 15);
        Vt[c * 72 + kk] = 0;
    }
    for (int t = lane; t < 49 * 4; t += 64) {
        int row = t >> 2, cb = (t & 3) * 8;
        const unsigned short* vp = src + (size_t)row * QKV_N + 768 + co + cb;
        ushort4 a = ((const ushort4*)vp)[0];
        ushort4 b = ((const ushort4*)vp)[1];
        Vt[(cb + 0) * 72 + row] = a.x; Vt[(cb + 1) * 72 + row] = a.y;
        Vt[(cb + 2) * 72 + row] = a.z; Vt[(cb + 3) * 72 + row] = a.w;
        Vt[(cb + 4) * 72 + row] = b.x; Vt[(cb + 5) * 72 + row] = b.y;
        Vt[(cb + 6) * 72 + row] = b.z; Vt[(cb + 7) * 72 + row] = b.w;
    }

    bf16x8 qf[4], kf[4];
#pragma unroll
    for (int mt = 0; mt < 4; ++mt) {
        int r = mt * 16 + l15; if (r > 48) r = 48;
        qf[mt] = ld8(src + (size_t)r * QKV_N + co + g * 8);
    }
#pragma unroll
    for (int nt = 0; nt < 4; ++nt) {
        int r = nt * 16 + l15; if (r > 48) r = 48;
        kf[nt] = ld8(src + (size_t)r * QKV_N + CH + co + g * 8);
    }

    f32x4 sa[4][4];
#pragma unroll
    for (int mt = 0; mt < 4; ++mt)
#pragma unroll
        for (int nt = 0; nt < 4; ++nt) sa[mt][nt] = (f32x4){0.f, 0.f, 0.f, 0.f};
#pragma unroll
    for (int mt = 0; mt < 4; ++mt)
#pragma unroll
        for (int nt = 0; nt < 4; ++nt)
            sa[mt][nt] = __builtin_amdgcn_mfma_f32_16x16x32_bf16(
                    qf[mt], kf[nt], sa[mt][nt], 0, 0, 0);

    int jj[4], jh[4], jw4[4];
#pragma unroll
    for (int nt = 0; nt < 4; ++nt) {
        int j = nt * 16 + l15;
        jj[nt] = j; jh[nt] = j / 7; jw4[nt] = j - (j / 7) * 7;
    }
    const float scale = 0.17677669529663687f;
#pragma unroll
    for (int mt = 0; mt < 4; ++mt) {
#pragma unroll
        for (int r = 0; r < 4; ++r) {
            int i = mt * 16 + g * 4 + r;
            int ic = i < 49 ? i : 48;
            int ih = ic / 7, iw = ic - (ic / 7) * 7;
            const float* mrow = mask + (size_t)wimg * 2401 + ic * 49;
            float sv[4];
#pragma unroll
            for (int nt = 0; nt < 4; ++nt) {
                float s = sa[mt][nt][r];
                if (jj[nt] < 49) {
                    int idx = (ih - jh[nt] + 6) * 13 + (iw - jw4[nt] + 6);
                    s = s * scale + btab[idx * 12 + h] + mrow[jj[nt]];
                } else s = -1e30f;
                sv[nt] = s;
            }
            float mx = fmaxf(fmaxf(sv[0], sv[1]), fmaxf(sv[2], sv[3]));
#pragma unroll
            for (int d = 1; d < 16; d <<= 1) mx = fmaxf(mx, __shfl_xor(mx, d));
            float sum = 0.f;
#pragma unroll
            for (int nt = 0; nt < 4; ++nt) { sv[nt] = __expf(sv[nt] - mx); sum += sv[nt]; }
#pragma unroll
            for (int d = 1; d < 16; d <<= 1) sum += __shfl_xor(sum, d);
            float inv = 1.0f / sum;
#pragma unroll
            for (int nt = 0; nt < 4; ++nt)
                Pw[i * 72 + nt * 16 + l15] = f2b(sv[nt] * inv);
        }
    }
    __syncthreads();

    f32x4 oa[4][2];
#pragma unroll
    for (int mt = 0; mt < 4; ++mt)
#pragma unroll
        for (int nt = 0; nt < 2; ++nt) oa[mt][nt] = (f32x4){0.f, 0.f, 0.f, 0.f};
#pragma unroll
    for (int ks = 0; ks < 2; ++ks) {
        bf16x8 pf[4];
#pragma unroll
        for (int mt = 0; mt < 4; ++mt)
            pf[mt] = ld8(Pw + (mt * 16 + l15) * 72 + ks * 32 + g * 8);
#pragma unroll
        for (int nt = 0; nt < 2; ++nt) {
            bf16x8 vf = ld8(Vt + (nt * 16 + l15) * 72 + ks * 32 + g * 8);
#pragma unroll
            for (int mt = 0; mt < 4; ++mt)
                oa[mt][nt] = __builtin_amdgcn_mfma_f32_16x16x32_bf16(
                        pf[mt], vf, oa[mt][nt], 0, 0, 0);
        }
    }

#pragma unroll
    for (int mt = 0; mt < 4; ++mt)
#pragma unroll
        for (int r = 0; r < 4; ++r) {
            int i = mt * 16 + g * 4 + r;
            if (i < 49) {
#pragma unroll
                for (int nt = 0; nt < 2; ++nt)
                    src[(size_t)i * QKV_N + co + nt * 16 + l15] = f2b(oa[mt][nt][r]);
            }
        }
}

extern "C" void kernel_launch(void* const* d_in, const int* in_sizes, int n_in,
                              void* d_out, int out_size, void* d_ws, size_t ws_size,
                              hipStream_t stream) {
    const float* x      = (const float*)d_in[0];
    const float* mask   = (const float*)d_in[1];
    const float* qkv_w  = (const float*)d_in[2];
    const float* qkv_b  = (const float*)d_in[3];
    const float* proj_w = (const float*)d_in[4];
    const float* proj_b = (const float*)d_in[5];
    const float* btab   = (const float*)d_in[6];
    float* out = (float*)d_out;

    unsigned short* wq_bt = (unsigned short*)d_ws;
    unsigned short* wp_bt = wq_bt + QKV_N * CH;
    unsigned short* base  = wp_bt + CH * CH;
    const size_t fixed = (size_t)(QKV_N * CH + CH * CH) * 2;
    const size_t unit  = (size_t)UNIT_ROWS * (CH + QKV_N) * 2;
    if (ws_size < fixed + unit) return;
    int upc = (int)((ws_size - fixed) / unit);
    if (upc > 64) upc = 64;
    unsigned short* xb  = base;
    unsigned short* qkv = base + (size_t)upc * UNIT_ROWS * CH;

    const int smem2 = 4 * 6912 * 2;   // 55,296 B -> 2 blocks/CU
    hipFuncSetAttribute(reinterpret_cast<const void*>(k_attn),
                        hipFuncAttributeMaxDynamicSharedMemorySize, smem2);

    dim3 blk(256);
    k_cvt_w<<<dim3((QKV_N * CH + 255) / 256), blk, 0, stream>>>(qkv_w, proj_w, wq_bt, wp_bt);

    for (int u0 = 0; u0 < 64; u0 += upc) {
        int units = (64 - u0) < upc ? (64 - u0) : upc;
        int m_base = u0 * UNIT_ROWS;
        int Mc = units * UNIT_ROWS;
        int mtiles = (Mc + 127) / 128;
        k_cvt<<<dim3(2048), blk, 0, stream>>>(x + (size_t)m_base * CH, xb, Mc * 48);
        k_gemm<0><<<dim3(mtiles * 9), blk, 0, stream>>>(
                xb, CH, wq_bt, CH, qkv_b, qkv, nullptr, QKV_N, Mc, 9, mtiles);
        k_attn<<<dim3(units * 192), blk, smem2, stream>>>(qkv, mask, btab, u0);
        k_gemm<1><<<dim3(mtiles * 3), blk, 0, stream>>>(
                qkv, QKV_N, wp_bt, CH, proj_b, nullptr, out + (size_t)m_base * CH,
                CH, Mc, 3, mtiles);
    }
}